// Round 15
// baseline (267.358 us; speedup 1.0000x reference)
//
#include <hip/hip_runtime.h>

#define BATCH 16
#define CH    64
#define TLEN  200
#define NP    30
#define HID   128
#define NSEQ  (BATCH * NP)   // 480
#define HP    144            // hz (f16) row pitch in halves (288 B)
#define H8P   160            // hz8 (fp8) row pitch in bytes
#define XP    72             // xlds row pitch in halves (144 B)
#define XGW   520            // xgb row pitch in floats (2080 B -> 8-bank rotation)

typedef _Float16 half8 __attribute__((ext_vector_type(8)));
typedef float    f32x4 __attribute__((ext_vector_type(4)));
typedef int      i32x8 __attribute__((ext_vector_type(8)));
typedef unsigned char u8;

__device__ __forceinline__ float sigm_fast(float x) {
    return __builtin_amdgcn_rcpf(1.0f + __expf(-x));
}
__device__ __forceinline__ float tanh_fast(float x) {
    return 1.0f - 2.0f * __builtin_amdgcn_rcpf(__expf(2.0f * x) + 1.0f);
}
__device__ __forceinline__ half8 cvt8(float4 a, float4 b) {
    return (half8){(_Float16)a.x,(_Float16)a.y,(_Float16)a.z,(_Float16)a.w,
                   (_Float16)b.x,(_Float16)b.y,(_Float16)b.z,(_Float16)b.w};
}

#define MFMA16(A,B,C) __builtin_amdgcn_mfma_f32_16x16x32_f16((A),(B),(C),0,0,0)
// fmt 0 = fp8 e4m3 (OCP), e8m0 scale 127 = x1.0
#define MFMA8(A,B,C) __builtin_amdgcn_mfma_scale_f32_16x16x128_f8f6f4((A),(B),(C),0,0,0,127,0,127)

// ---------------------------------------------------------------------------
// Fused LSTM r15: break the barrier phase-lock WITHOUT r14's register spill.
// 480 blocks x 512 threads (8 waves), ONE sequence per block, ~63 KB LDS,
// __launch_bounds__(512,4) -> TWO independent blocks per CU (4 waves/SIMD).
// Per-wave layout = r13's register-lean one (16 cols/wave, ~76 weight VGPRs,
// 112 total measured -> fits the 128 cap; r14 spilled at 152+ and died on
// 81 MB of scratch traffic, WRITE_SIZE is the no-spill check here).
// r13 exposed ~720 cy/step with both pipes idle, all waves lockstepped on the
// block barrier; sibling-block waves now fill those stalls (independent
// barriers).
//   - i,f,o gates: one fp8-e4m3 K=128 scaled MFMA each (absmax 0.0039, r13);
//     g stays f16 (4-chain). h dual-stored f16+fp8; A rows: row0=h, rest
//     shared ZERO row (broadcast reads).
//   - x LDS-resident (28.8 KB, one-time gather); xg per-8-step f16 burst.
// ---------------------------------------------------------------------------
__global__ __launch_bounds__(512, 4) void fused_lstm(
    const float* __restrict__ x, const float* __restrict__ W_ih,
    const float* __restrict__ W_hh, const float* __restrict__ b_ih,
    const float* __restrict__ b_hh, const float* __restrict__ W_fc,
    const float* __restrict__ b_fc, float* __restrict__ out)
{
    const int tid = threadIdx.x;
    const int w  = tid >> 6;     // wave 0..7 -> owns gate sub-cols 16w+lr
    const int l  = tid & 63;
    const int lr = l & 15;
    const int lq = l >> 4;

    // XCD-chunked swizzle: XCD c gets seqs c*60..c*60+59 (480 % 8 == 0 -> bijective)
    const int blk = blockIdx.x;
    const int n   = (blk & 7) * 60 + (blk >> 3);
    const int b0  = n / NP;
    const int p0  = n % NP;

    __shared__ __align__(16) _Float16 hz[3][HP];        // row0=buf0 h, row1=buf1 h, row2=ZERO
    __shared__ __align__(16) u8       hz8[3][H8P];      // fp8 h, same scheme
    __shared__ __align__(16) _Float16 xlds[TLEN][XP];   // 28.8 KB, this seq's x
    __shared__ __align__(16) float    xgb[2][8][XGW];   // 33.3 KB, xg+bias f32, row=step

    // ---- W fragments in registers (r13 footprint: ~76 VGPRs) ----
    i32x8 b8i, b8f, b8o;      // fp8 W_hh rows for i,f,o (col 128T+16w+lr, K=32lq..+32)
    {
        const int Ts[3] = {0, 1, 3};
        i32x8* dst[3] = {&b8i, &b8f, &b8o};
#pragma unroll
        for (int q = 0; q < 3; ++q) {
            const float* rw = W_hh + (size_t)(128*Ts[q] + 16*w + lr) * HID + 32*lq;
            i32x8 pk;
#pragma unroll
            for (int r = 0; r < 8; ++r) {
                int v = __builtin_amdgcn_cvt_pk_fp8_f32(rw[4*r],     rw[4*r + 1], 0, false);
                v     = __builtin_amdgcn_cvt_pk_fp8_f32(rw[4*r + 2], rw[4*r + 3], v, true);
                pk[r] = v;
            }
            *dst[q] = pk;
        }
    }
    half8 bg16[4];            // f16 W_hh for g-gate, K-chunks
    {
        const float* rh = W_hh + (size_t)(256 + 16*w + lr) * HID;
#pragma unroll
        for (int kt = 0; kt < 4; ++kt) {
            const int k0 = 32*kt + 8*lq;
            bg16[kt] = cvt8(*(const float4*)(rh + k0), *(const float4*)(rh + k0 + 4));
        }
    }
    half8 bih[4][2];          // f16 W_ih, gate x K-chunk (K=64)
    float biasx[4];
#pragma unroll
    for (int T = 0; T < 4; ++T) {
        const int g = 128*T + 16*w + lr;
        const float* ri = W_ih + (size_t)g * CH;
#pragma unroll
        for (int j = 0; j < 2; ++j) {
            const int k0 = 32*j + 8*lq;
            bih[T][j] = cvt8(*(const float4*)(ri + k0), *(const float4*)(ri + k0 + 4));
        }
        biasx[T] = b_ih[g] + b_hh[g];
    }

    // zero h buffers (rows 0,1 = h_0 = 0; row 2 = permanent zero row)
    if (tid < (3 * HP) / 2) ((unsigned*)hz)[tid] = 0u;
    if (tid < (3 * H8P) / 4) ((unsigned*)hz8)[tid] = 0u;

    // ---- prologue: stage this seq's x into LDS (one-time gather; lines are
    // L2-shared by the ~30 same-b0 blocks on this XCD via the swizzle)
    for (int e = tid; e < CH * TLEN; e += 512) {
        const int t = e % TLEN, c = e / TLEN;
        xlds[t][c] = (_Float16)x[((size_t)(b0 * CH + c) * TLEN + t) * NP + p0];
    }
    float cst = 0.f;                        // c-state: valid in lanes l<16
    const int hcol = 16*w + lr;
    // A-frag source rows: lr==0 -> real h row, else shared ZERO row.
    const _Float16* hpA  = &hz[(lr == 0) ? 0 : 2][8 * lq];
    const _Float16* hpB  = &hz[(lr == 0) ? 1 : 2][8 * lq];
    const u8*       hp8A = &hz8[(lr == 0) ? 0 : 2][32 * lq];
    const u8*       hp8B = &hz8[(lr == 0) ? 1 : 2][32 * lq];
    __syncthreads();                        // h buffers + xlds resident

    // per-period xg GEMM: A rows (lr&7) = step offsets (rows 8-15 duplicates);
    // C row (4lq+r) = step, col lr = this wave's gate sub-col. lq<2 stores.
#define XG_BURST(P, TB) {                                                         \
        const _Float16* xr_ = &xlds[8*(P) + (lr & 7)][8*lq];                      \
        half8 xf0_ = *(const half8*)xr_;                                          \
        half8 xf1_ = *(const half8*)(xr_ + 32);                                   \
        f32x4 ac_[4];                                                             \
        _Pragma("unroll") for (int T_ = 0; T_ < 4; ++T_) {                        \
            f32x4 a_ = {biasx[T_], biasx[T_], biasx[T_], biasx[T_]};              \
            a_ = MFMA16(xf0_, bih[T_][0], a_);                                    \
            a_ = MFMA16(xf1_, bih[T_][1], a_);                                    \
            ac_[T_] = a_;                                                         \
        }                                                                         \
        if (lq < 2) {                                                             \
            _Pragma("unroll") for (int r_ = 0; r_ < 4; ++r_) {                    \
                float* dst_ = &xgb[TB][4*lq + r_][hcol * 4];                      \
                *(f32x4*)dst_ = (f32x4){ac_[0][r_], ac_[1][r_],                   \
                                        ac_[2][r_], ac_[3][r_]};                  \
            }                                                                     \
        } }

    XG_BURST(0, 0)          // xg for period 0
    __syncthreads();

#pragma unroll 1
    for (int p = 0; p < 25; ++p) {
        const int pe = p & 1;
#pragma unroll
        for (int k = 0; k < 8; ++k) {
            const int cur = k & 1;       // t = 8p+k, t&1 = k&1
            const int nxt = cur ^ 1;
            // lane's 4 gate xg values (f32 quad; lanes >=16 read duplicates)
            f32x4 xg4 = *(const f32x4*)&xgb[pe][k][hcol * 4];
            // A fragments: fp8 (32 B) for i,f,o; f16 chunks for g
            i32x8 a8 = *(const i32x8*)(cur ? hp8B : hp8A);
            const _Float16* hr = cur ? hpB : hpA;
            half8 a0 = *(const half8*)(hr);
            half8 a1 = *(const half8*)(hr + 32);
            half8 a2 = *(const half8*)(hr + 64);
            half8 a3 = *(const half8*)(hr + 96);
            f32x4 zz = {0.f, 0.f, 0.f, 0.f};
            __builtin_amdgcn_s_setprio(1);
            // i,f: one K=128 fp8 MFMA each; g: f16 chain — all EARLY
            f32x4 ci = MFMA8(a8, b8i, zz);
            f32x4 cf = MFMA8(a8, b8f, zz);
            f32x4 cg = MFMA16(a0, bg16[0], zz);
            cg = MFMA16(a1, bg16[1], cg);
            cg = MFMA16(a2, bg16[2], cg);
            cg = MFMA16(a3, bg16[3], cg);
            // early act front (all lanes; lanes >=16 garbage, writes masked)
            float si = sigm_fast(ci[0] + xg4[0]);
            float sf = sigm_fast(cf[0] + xg4[1]);
            float tg = tanh_fast(cg[0] + xg4[2]);
            float cnew = sf * cst + si * tg;
            // o-gate LAST
            f32x4 co = MFMA8(a8, b8o, zz);
            __builtin_amdgcn_s_setprio(0);
            if (k == 0 && p < 24) XG_BURST(p + 1, pe ^ 1)    // xg for period p+1
            // tail: sigm(go) || tanh(c) -> mul -> cvt -> writes (f16 + fp8)
            float hv = sigm_fast(co[0] + xg4[3]) * tanh_fast(cnew);
            cst = cnew;
            if (l < 16) {
                hz[nxt][hcol] = (_Float16)hv;
                hz8[nxt][hcol] = (u8)__builtin_amdgcn_cvt_pk_fp8_f32(hv, hv, 0, false);
            }
            __syncthreads();
        }
    }

    // FC epilogue: h_200 in hz row 0 (t=199 wrote nxt=0)
    if (tid < CH) {
        const int ch = tid;
        const float* wf = W_fc + (size_t)ch * HID;
        float acc = b_fc[ch];
#pragma unroll
        for (int j8 = 0; j8 < 16; ++j8) {
            half8 hv = *(const half8*)&hz[0][8 * j8];
            float4 w0 = *(const float4*)(wf + 8 * j8);
            float4 w1 = *(const float4*)(wf + 8 * j8 + 4);
            acc += w0.x * (float)hv[0] + w0.y * (float)hv[1]
                 + w0.z * (float)hv[2] + w0.w * (float)hv[3]
                 + w1.x * (float)hv[4] + w1.y * (float)hv[5]
                 + w1.z * (float)hv[6] + w1.w * (float)hv[7];
        }
        out[(size_t)n * CH + ch] = acc;
    }
}

extern "C" void kernel_launch(void* const* d_in, const int* in_sizes, int n_in,
                              void* d_out, int out_size, void* d_ws, size_t ws_size,
                              hipStream_t stream) {
    (void)in_sizes; (void)n_in; (void)out_size; (void)d_ws; (void)ws_size;
    fused_lstm<<<NSEQ, 512, 0, stream>>>(
        (const float*)d_in[0], (const float*)d_in[1], (const float*)d_in[2],
        (const float*)d_in[3], (const float*)d_in[4], (const float*)d_in[5],
        (const float*)d_in[6], (float*)d_out);
}